// Round 2
// baseline (1294.796 us; speedup 1.0000x reference)
//
#include <hip/hip_runtime.h>
#include <stdint.h>
#include <stddef.h>

// out = x @ (base_kernel + 2.0*kron(A@B, O)) + bias  -- ONE bf16 GEMM.
// x: (16384 x 4096) f32, W: (4096 x 4096) f32, out f32.

#define M_TOT 16384
#define K_TOT 4096
#define N_TOT 4096
#define SCALING 2.0f

typedef __attribute__((ext_vector_type(8))) short bf16x8;     // MFMA A/B frag (4 VGPRs)
typedef __attribute__((ext_vector_type(16))) float floatx16;  // 32x32 MFMA C/D frag
typedef __attribute__((ext_vector_type(4))) float floatx4;

__device__ __forceinline__ unsigned short f32_to_bf16(float f) {
  union { float f; unsigned int u; } v; v.f = f;
  unsigned int r = 0x7fffu + ((v.u >> 16) & 1u);  // RNE
  return (unsigned short)((v.u + r) >> 16);
}

// 16-byte async global->LDS (global_load_lds_dwordx4). LDS dest = wave base + lane*16.
__device__ __forceinline__ void async_copy16(const void* gsrc, void* ldst) {
  __builtin_amdgcn_global_load_lds(
      (const __attribute__((address_space(1))) void*)(uintptr_t)gsrc,
      (__attribute__((address_space(3))) void*)(uintptr_t)ldst,
      16, 0, 0);
}

// ---- Kernel 1: wl = SCALING * (lora_A @ lora_B), 16x16 fp32 ----
__global__ void wleft_kernel(const float* __restrict__ A, const float* __restrict__ B,
                             float* __restrict__ wl) {
  int i = threadIdx.x >> 4, j = threadIdx.x & 15;
  float s = 0.f;
#pragma unroll
  for (int k = 0; k < 16; ++k) s += A[i * 16 + k] * B[k * 16 + j];
  wl[threadIdx.x] = s * SCALING;
}

// ---- Kernel 2: Wt[n][k] = bf16( base[k][n] + wl[k>>8][n>>8]*O[k&255][n&255] ) ----
__global__ void prep_w_kernel(const float* __restrict__ base, const float* __restrict__ O,
                              const float* __restrict__ wl, unsigned short* __restrict__ Wt) {
  __shared__ float tile[32][33];
  int n0 = blockIdx.x * 32, k0 = blockIdx.y * 32;
  int tx = threadIdx.x, ty = threadIdx.y;  // (32, 8)
#pragma unroll
  for (int r = 0; r < 32; r += 8) {
    int k = k0 + ty + r, n = n0 + tx;
    float v = base[(size_t)k * N_TOT + n]
            + wl[((k >> 8) << 4) + (n >> 8)] * O[((size_t)(k & 255) << 8) + (n & 255)];
    tile[ty + r][tx] = v;
  }
  __syncthreads();
#pragma unroll
  for (int r = 0; r < 32; r += 8) {
    int n = n0 + ty + r, k = k0 + tx;
    Wt[(size_t)n * K_TOT + k] = f32_to_bf16(tile[tx][ty + r]);
  }
}

// ---- Kernel 3: x f32 -> bf16 ----
__global__ void cvt_x_kernel(const float* __restrict__ x, unsigned short* __restrict__ xb) {
  size_t i = ((size_t)blockIdx.x * blockDim.x + threadIdx.x) * 8;
  float4 a = *(const float4*)(x + i);
  float4 b = *(const float4*)(x + i + 4);
  union { bf16x8 v; unsigned short h[8]; } u;
  u.h[0] = f32_to_bf16(a.x); u.h[1] = f32_to_bf16(a.y);
  u.h[2] = f32_to_bf16(a.z); u.h[3] = f32_to_bf16(a.w);
  u.h[4] = f32_to_bf16(b.x); u.h[5] = f32_to_bf16(b.y);
  u.h[6] = f32_to_bf16(b.z); u.h[7] = f32_to_bf16(b.w);
  *(bf16x8*)(xb + i) = u.v;
}

// ---- Kernel 4: C = Xb(MxK) @ Wt(NxK)^T + bias ----
// 128x128 block, BK=32, 4 waves 2x2, each wave 64x64 = 2x2 x mfma_f32_32x32x16_bf16.
// LDS chunk swizzle: slot (row, s) holds global k-chunk (s ^ ((row>>1)&3)) -> all 32
// banks covered across 8 rows; frag ds_read_b128 conflict-free. Source permutation only
// (same 64B lines per row) so global coalescing and the global_load_lds lane->slot
// contract (base + lane*16) are both preserved.
__global__ __launch_bounds__(256) void gemm_bt_kernel(
    const unsigned short* __restrict__ Xb, const unsigned short* __restrict__ Wt,
    const float* __restrict__ bias, float* __restrict__ out) {
  __shared__ __align__(16) unsigned short Alds[128 * 32];
  __shared__ __align__(16) unsigned short Blds[128 * 32];

  const int tid = threadIdx.x;
  const int lane = tid & 63;
  const int wave = tid >> 6;
  const int lane31 = lane & 31, khalf = lane >> 5;
  const int wm = wave & 1, wn = wave >> 1;

  // Block swizzle: groups of 256 blocks = 8 m-rows x 32 n-cols, m-fastest.
  // With round-robin block->XCD, each XCD keeps ~1 Xb row-block hot in its L2.
  const int bid = blockIdx.x;
  const int grp = bid >> 8, loc = bid & 255;
  const int m0 = (grp * 8 + (loc & 7)) * 128;
  const int n0 = (loc >> 3) * 128;

  floatx16 acc[2][2];
#pragma unroll
  for (int i = 0; i < 2; ++i)
#pragma unroll
    for (int j = 0; j < 2; ++j)
#pragma unroll
      for (int r = 0; r < 16; ++r) acc[i][j][r] = 0.f;

  // Staging source indices (fixed per thread): slot c -> row=c>>2, s=c&3,
  // global k-chunk kc = s ^ ((row>>1)&3).
  int c0 = tid, c1 = 256 + tid;
  int r0 = c0 >> 2, s0 = c0 & 3, kc0 = s0 ^ ((r0 >> 1) & 3);
  int r1 = c1 >> 2, s1 = c1 & 3, kc1 = s1 ^ ((r1 >> 1) & 3);
  const unsigned short* srcA0 = Xb + (size_t)(m0 + r0) * K_TOT + kc0 * 8;
  const unsigned short* srcA1 = Xb + (size_t)(m0 + r1) * K_TOT + kc1 * 8;
  const unsigned short* srcB0 = Wt + (size_t)(n0 + r0) * K_TOT + kc0 * 8;
  const unsigned short* srcB1 = Wt + (size_t)(n0 + r1) * K_TOT + kc1 * 8;

  // Frag LDS offsets (bf16 units), fixed per thread per tile: row*32 + slot*8.
  int arow0 = wm * 64 + 0 * 32 + lane31, arow1 = wm * 64 + 1 * 32 + lane31;
  int brow0 = wn * 64 + 0 * 32 + lane31, brow1 = wn * 64 + 1 * 32 + lane31;
  int aswz0 = (arow0 >> 1) & 3, aswz1 = (arow1 >> 1) & 3;
  int bswz0 = (brow0 >> 1) & 3, bswz1 = (brow1 >> 1) & 3;

  for (int k0 = 0; k0 < K_TOT; k0 += 32) {
    async_copy16(srcA0, Alds + (size_t)c0 * 8);
    async_copy16(srcA1, Alds + (size_t)c1 * 8);
    async_copy16(srcB0, Blds + (size_t)c0 * 8);
    async_copy16(srcB1, Blds + (size_t)c1 * 8);
    srcA0 += 32; srcA1 += 32; srcB0 += 32; srcB1 += 32;
    __syncthreads();

#pragma unroll
    for (int t = 0; t < 2; ++t) {
      int jj = 2 * t + khalf;  // k-chunk index for this half-wave
      bf16x8 a0 = *(const bf16x8*)(Alds + arow0 * 32 + (jj ^ aswz0) * 8);
      bf16x8 a1 = *(const bf16x8*)(Alds + arow1 * 32 + (jj ^ aswz1) * 8);
      bf16x8 b0 = *(const bf16x8*)(Blds + brow0 * 32 + (jj ^ bswz0) * 8);
      bf16x8 b1 = *(const bf16x8*)(Blds + brow1 * 32 + (jj ^ bswz1) * 8);
      acc[0][0] = __builtin_amdgcn_mfma_f32_32x32x16_bf16(a0, b0, acc[0][0], 0, 0, 0);
      acc[0][1] = __builtin_amdgcn_mfma_f32_32x32x16_bf16(a0, b1, acc[0][1], 0, 0, 0);
      acc[1][0] = __builtin_amdgcn_mfma_f32_32x32x16_bf16(a1, b0, acc[1][0], 0, 0, 0);
      acc[1][1] = __builtin_amdgcn_mfma_f32_32x32x16_bf16(a1, b1, acc[1][1], 0, 0, 0);
    }
    __syncthreads();
  }

  // Epilogue: C/D layout col = lane&31, row = (reg&3) + 8*(reg>>2) + 4*(lane>>5).
#pragma unroll
  for (int nt = 0; nt < 2; ++nt) {
    int col = n0 + wn * 64 + nt * 32 + lane31;
    float bv = bias[col];
#pragma unroll
    for (int mt = 0; mt < 2; ++mt) {
      int rowbase = m0 + wm * 64 + mt * 32 + 4 * khalf;
#pragma unroll
      for (int rg = 0; rg < 4; ++rg) {
#pragma unroll
        for (int rr = 0; rr < 4; ++rr) {
          int row = rowbase + 8 * rg + rr;
          out[(size_t)row * N_TOT + col] = acc[mt][nt][rg * 4 + rr] + bv;
        }
      }
    }
  }
}

extern "C" void kernel_launch(void* const* d_in, const int* in_sizes, int n_in,
                              void* d_out, int out_size, void* d_ws, size_t ws_size,
                              hipStream_t stream) {
  const float* x    = (const float*)d_in[0];
  const float* base = (const float*)d_in[1];
  const float* bias = (const float*)d_in[2];
  const float* lA   = (const float*)d_in[3];
  const float* lB   = (const float*)d_in[4];
  const float* O    = (const float*)d_in[5];
  float* out = (float*)d_out;

  char* ws = (char*)d_ws;
  unsigned short* Xb = (unsigned short*)ws;                                   // 128 MB
  unsigned short* Wt = (unsigned short*)(ws + (size_t)M_TOT * K_TOT * 2);     // 32 MB
  float* wl = (float*)(ws + (size_t)M_TOT * K_TOT * 2 + (size_t)N_TOT * K_TOT * 2);

  wleft_kernel<<<1, 256, 0, stream>>>(lA, lB, wl);
  prep_w_kernel<<<dim3(N_TOT / 32, K_TOT / 32), dim3(32, 8), 0, stream>>>(base, O, wl, Wt);
  cvt_x_kernel<<<((size_t)M_TOT * K_TOT) / 8 / 256, 256, 0, stream>>>(x, Xb);
  gemm_bt_kernel<<<(M_TOT / 128) * (N_TOT / 128), 256, 0, stream>>>(Xb, Wt, bias, out);
}

// Round 3
// 1148.604 us; speedup vs baseline: 1.1273x; 1.1273x over previous
//
#include <hip/hip_runtime.h>
#include <stdint.h>
#include <stddef.h>

// out = x @ (base_kernel + 2.0*kron(A@B, O)) + bias  -- ONE bf16 GEMM.
// x: (16384 x 4096) f32, W: (4096 x 4096) f32, out f32.

#define M_TOT 16384
#define K_TOT 4096
#define N_TOT 4096
#define SCALING 2.0f

typedef __attribute__((ext_vector_type(8))) short bf16x8;   // MFMA A/B frag (4 VGPRs)
typedef __attribute__((ext_vector_type(4))) float floatx4;  // 16x16 MFMA C/D frag

__device__ __forceinline__ unsigned short f32_to_bf16(float f) {
  union { float f; unsigned int u; } v; v.f = f;
  unsigned int r = 0x7fffu + ((v.u >> 16) & 1u);  // RNE
  return (unsigned short)((v.u + r) >> 16);
}

// 16-byte async global->LDS (global_load_lds_dwordx4). LDS dest = wave base + lane*16.
__device__ __forceinline__ void async_copy16(const void* gsrc, void* ldst) {
  __builtin_amdgcn_global_load_lds(
      (const __attribute__((address_space(1))) void*)(uintptr_t)gsrc,
      (__attribute__((address_space(3))) void*)(uintptr_t)ldst,
      16, 0, 0);
}

// ---- Kernel 1: wl = SCALING * (lora_A @ lora_B), 16x16 fp32 ----
__global__ void wleft_kernel(const float* __restrict__ A, const float* __restrict__ B,
                             float* __restrict__ wl) {
  int i = threadIdx.x >> 4, j = threadIdx.x & 15;
  float s = 0.f;
#pragma unroll
  for (int k = 0; k < 16; ++k) s += A[i * 16 + k] * B[k * 16 + j];
  wl[threadIdx.x] = s * SCALING;
}

// ---- Kernel 2: Wt[n][k] = bf16( base[k][n] + wl[k>>8][n>>8]*O[k&255][n&255] ) ----
__global__ void prep_w_kernel(const float* __restrict__ base, const float* __restrict__ O,
                              const float* __restrict__ wl, unsigned short* __restrict__ Wt) {
  __shared__ float tile[32][33];
  int n0 = blockIdx.x * 32, k0 = blockIdx.y * 32;
  int tx = threadIdx.x, ty = threadIdx.y;  // (32, 8)
#pragma unroll
  for (int r = 0; r < 32; r += 8) {
    int k = k0 + ty + r, n = n0 + tx;
    float v = base[(size_t)k * N_TOT + n]
            + wl[((k >> 8) << 4) + (n >> 8)] * O[((size_t)(k & 255) << 8) + (n & 255)];
    tile[ty + r][tx] = v;
  }
  __syncthreads();
#pragma unroll
  for (int r = 0; r < 32; r += 8) {
    int n = n0 + ty + r, k = k0 + tx;
    Wt[(size_t)n * K_TOT + k] = f32_to_bf16(tile[tx][ty + r]);
  }
}

// ---- Kernel 3: x f32 -> bf16 ----
__global__ void cvt_x_kernel(const float* __restrict__ x, unsigned short* __restrict__ xb) {
  size_t i = ((size_t)blockIdx.x * blockDim.x + threadIdx.x) * 8;
  float4 a = *(const float4*)(x + i);
  float4 b = *(const float4*)(x + i + 4);
  union { bf16x8 v; unsigned short h[8]; } u;
  u.h[0] = f32_to_bf16(a.x); u.h[1] = f32_to_bf16(a.y);
  u.h[2] = f32_to_bf16(a.z); u.h[3] = f32_to_bf16(a.w);
  u.h[4] = f32_to_bf16(b.x); u.h[5] = f32_to_bf16(b.y);
  u.h[6] = f32_to_bf16(b.z); u.h[7] = f32_to_bf16(b.w);
  *(bf16x8*)(xb + i) = u.v;
}

// ---- Kernel 4: C = Xb(MxK) @ Wt(NxK)^T + bias ----
// 128x128 block, BK=64, 4 waves 2x2, each wave 64x64 = 4x4 x mfma_f32_16x16x32_bf16.
// LDS rows are 128B (64 bf16 = 8 chunks of 16B) -> a row spans all 32 banks.
// XOR swizzle: LDS slot (row, s) holds global k-chunk (s ^ (row&7)); frag reads then
// place consecutive lanes on disjoint 4-bank groups covering all 32 banks per 8-lane
// phase -> conflict-free. Source permutation stays within a 128B row, so global
// coalescing and the global_load_lds lane contract (base + lane*16) are preserved.
__global__ __launch_bounds__(256) void gemm_bt_kernel(
    const unsigned short* __restrict__ Xb, const unsigned short* __restrict__ Wt,
    const float* __restrict__ bias, float* __restrict__ out) {
  __shared__ __align__(16) unsigned short Alds[128 * 64];  // 16 KB
  __shared__ __align__(16) unsigned short Blds[128 * 64];  // 16 KB

  const int tid = threadIdx.x;
  const int wave = tid >> 6, lane = tid & 63;
  const int quad = lane >> 4, lanemod = lane & 15;
  const int wm = wave & 1, wn = wave >> 1;

  const int m0 = blockIdx.y * 128, n0 = blockIdx.x * 128;

  floatx4 acc[4][4];
#pragma unroll
  for (int i = 0; i < 4; ++i)
#pragma unroll
    for (int j = 0; j < 4; ++j) acc[i][j] = (floatx4){0.f, 0.f, 0.f, 0.f};

  // Staging: 128 rows x 8 chunks = 1024 chunks per matrix, 4 per thread.
  // chunk c: row = c>>3, slot s = c&7, global k-chunk kc = s ^ (row&7).
  const unsigned short* srcA[4];
  const unsigned short* srcB[4];
  int dst[4];
#pragma unroll
  for (int it = 0; it < 4; ++it) {
    int c = it * 256 + tid;
    int row = c >> 3, kc = (c & 7) ^ (row & 7);
    srcA[it] = Xb + (size_t)(m0 + row) * K_TOT + kc * 8;
    srcB[it] = Wt + (size_t)(n0 + row) * K_TOT + kc * 8;
    dst[it] = c * 8;  // u16 units; byte offset c*16 == wave base + lane*16
  }

  // Frag read bases (u16 units): row*64; swizzle key row&7.
  int aoff[4], bqoff[4], aswz[4], bswz[4];
#pragma unroll
  for (int t = 0; t < 4; ++t) {
    int ar = wm * 64 + t * 16 + lanemod;
    int br = wn * 64 + t * 16 + lanemod;
    aoff[t] = ar * 64; aswz[t] = ar & 7;
    bqoff[t] = br * 64; bswz[t] = br & 7;
  }

  for (int k0 = 0; k0 < K_TOT; k0 += 64) {
#pragma unroll
    for (int it = 0; it < 4; ++it) {
      async_copy16(srcA[it], Alds + dst[it]);
      async_copy16(srcB[it], Blds + dst[it]);
      srcA[it] += 64; srcB[it] += 64;
    }
    __syncthreads();

#pragma unroll
    for (int kk = 0; kk < 2; ++kk) {
      int j = kk * 4 + quad;  // global k-chunk index within the 8-chunk row
      bf16x8 af[4], bfr[4];
#pragma unroll
      for (int t = 0; t < 4; ++t) {
        af[t]  = *(const bf16x8*)(Alds + aoff[t]  + (j ^ aswz[t]) * 8);
        bfr[t] = *(const bf16x8*)(Blds + bqoff[t] + (j ^ bswz[t]) * 8);
      }
#pragma unroll
      for (int mt = 0; mt < 4; ++mt)
#pragma unroll
        for (int nt = 0; nt < 4; ++nt)
          acc[mt][nt] = __builtin_amdgcn_mfma_f32_16x16x32_bf16(af[mt], bfr[nt], acc[mt][nt], 0, 0, 0);
    }
    __syncthreads();
  }

  // Epilogue: C/D layout col = lane&15, row = quad*4 + reg. Fuse bias.
#pragma unroll
  for (int nt = 0; nt < 4; ++nt) {
    int col = n0 + wn * 64 + nt * 16 + lanemod;
    float bv = bias[col];
#pragma unroll
    for (int mt = 0; mt < 4; ++mt) {
      int row = m0 + wm * 64 + mt * 16 + quad * 4;
#pragma unroll
      for (int r = 0; r < 4; ++r)
        out[(size_t)(row + r) * N_TOT + col] = acc[mt][nt][r] + bv;
    }
  }
}

extern "C" void kernel_launch(void* const* d_in, const int* in_sizes, int n_in,
                              void* d_out, int out_size, void* d_ws, size_t ws_size,
                              hipStream_t stream) {
  const float* x    = (const float*)d_in[0];
  const float* base = (const float*)d_in[1];
  const float* bias = (const float*)d_in[2];
  const float* lA   = (const float*)d_in[3];
  const float* lB   = (const float*)d_in[4];
  const float* O    = (const float*)d_in[5];
  float* out = (float*)d_out;

  char* ws = (char*)d_ws;
  unsigned short* Xb = (unsigned short*)ws;                                   // 128 MB
  unsigned short* Wt = (unsigned short*)(ws + (size_t)M_TOT * K_TOT * 2);     // 32 MB
  float* wl = (float*)(ws + (size_t)M_TOT * K_TOT * 2 + (size_t)N_TOT * K_TOT * 2);

  wleft_kernel<<<1, 256, 0, stream>>>(lA, lB, wl);
  prep_w_kernel<<<dim3(N_TOT / 32, K_TOT / 32), dim3(32, 8), 0, stream>>>(base, O, wl, Wt);
  cvt_x_kernel<<<((size_t)M_TOT * K_TOT) / 8 / 256, 256, 0, stream>>>(x, Xb);
  gemm_bt_kernel<<<dim3(N_TOT / 128, M_TOT / 128), 256, 0, stream>>>(Xb, Wt, bias, out);
}